// Round 3
// baseline (138.516 us; speedup 1.0000x reference)
//
#include <hip/hip_runtime.h>
#include <hip/hip_bf16.h>
#include <math.h>

// Polynomial feature map: Xp = X @ P; out = [bias | Xp | Xp^2 | Xp^3 | pairs | sqrt(|Xp|+eps)]
// X: [16384, 2048] f32, P: [2048, 512] f32, out: [16384, 2561] f32.
// pairs (triu k=1, first 512): c<511 -> Xp[:,0]*Xp[:,c+1]; c==511 -> Xp[:,1]*Xp[:,2]
//
// Path: prep_b (P -> Bt bf16 [512][2048] in ws) ; gemm3 (BM=64 x BN=128, dbuf, grid 1024,
// 4 blocks/CU) writes p1 ; epi_k expands the other regions reading p1 (L2/L3-hot).

typedef __attribute__((ext_vector_type(4))) float f32x4;
typedef __attribute__((ext_vector_type(8))) short bf16x8;

#define MM 16384
#define NN 512
#define KK 2048
#define OUTW 2561

#define BM 64
#define BN 128
#define BK 32
#define NT (KK / BK)  // 64

__device__ __forceinline__ short f2bf(float x) {
  union { __hip_bfloat16 b; short s; } u;
  u.b = __float2bfloat16(x);  // hw RNE; compiler pairs into v_cvt_pk_bf16_f32
  return u.s;
}

__device__ __forceinline__ bf16x8 cvt8(f32x4 a, f32x4 b) {
  bf16x8 r;
  r[0] = f2bf(a[0]); r[1] = f2bf(a[1]); r[2] = f2bf(a[2]); r[3] = f2bf(a[3]);
  r[4] = f2bf(b[0]); r[5] = f2bf(b[1]); r[6] = f2bf(b[2]); r[7] = f2bf(b[3]);
  return r;
}

__device__ __forceinline__ void gl_lds16(const void* g, void* l) {
  __builtin_amdgcn_global_load_lds((const __attribute__((address_space(1))) unsigned int*)g,
                                   (__attribute__((address_space(3))) unsigned int*)l, 16, 0, 0);
}

// ---------------- prep: P [K][N] f32 -> Bt [N][K] bf16 ----------------
__global__ __launch_bounds__(256) void prep_b(const float* __restrict__ P, short* __restrict__ Bt) {
  __shared__ float ts[64][65];
  const int tid = threadIdx.x;
  const int k0 = (blockIdx.x >> 3) * 64;  // 32 k-blocks
  const int n0 = (blockIdx.x & 7) * 64;   // 8 n-blocks
#pragma unroll
  for (int j = 0; j < 16; ++j) {
    int idx = j * 256 + tid;
    int kr = idx >> 6, nc = idx & 63;
    ts[kr][nc] = P[(size_t)(k0 + kr) * NN + n0 + nc];
  }
  __syncthreads();
#pragma unroll
  for (int j = 0; j < 16; ++j) {
    int idx = j * 256 + tid;
    int nr = idx >> 6, kc = idx & 63;
    Bt[(size_t)(n0 + nr) * KK + k0 + kc] = f2bf(ts[kc][nr]);
  }
}

// ---------------- GEMM: Xp -> out p1 region ----------------
// LDS tiles [rows][32 bf16] (64B rows, 4x 16B slots). Swizzle: slot' = slot ^ ((row>>1)&3)
// -> ideal 8-phase (conflict-free) on ds_read_b128 frags and ds_write_b128 staging.
// B staged by global_load_lds (linear dest); swizzle realized by permuting per-lane
// global source k-slot: src_slot = (lane&3) ^ ((lane>>3)&3)  (rule #21).
__global__ __launch_bounds__(256) void gemm3(const float* __restrict__ X,
                                             const short* __restrict__ Bt,
                                             float* __restrict__ out) {
  __shared__ short As[2][BM * BK];   // 4 KB each
  __shared__ short Bs[2][BN * BK];   // 8 KB each

  const int tid = threadIdx.x;
  const int wid = tid >> 6, lane = tid & 63;
  const int lrow = lane & 15, kh = lane >> 4;
  const int wr = wid >> 1, wc = wid & 1;  // 2x2 wave grid; wave tile 32 x 64

  // XCD-bijective swizzle (grid 1024, 1024%8==0): xcd gets contiguous tile chunk
  const int bid = blockIdx.x;
  const int tile = (bid & 7) * 128 + (bid >> 3);
  const int m0 = (tile >> 2) * BM;   // 256 row-blocks
  const int n0 = (tile & 3) * BN;    // 4 col-blocks (consecutive tiles share A rows)

  // A staging: thread -> row = tid>>2 (0..63), kq = tid&3; 32B global, one b128 LDS write
  const int arow = tid >> 2, akq = tid & 3;
  const float* aG = X + (size_t)(m0 + arow) * KK + akq * 8;
  const int aoff = arow * 32 + ((akq ^ ((arow >> 1) & 3)) << 3);  // shorts (16B slot)

  // B staging: 2 wave-loads/wave; load p covers B-rows (p*4+wid)*16 .. +15
  const int kd = (lane & 3) ^ ((lane >> 3) & 3);  // pre-swizzled source k-slot
  const short* bG[2];
  int bOff[2];
#pragma unroll
  for (int p = 0; p < 2; ++p) {
    int R0 = (p * 4 + wid) * 16;
    bOff[p] = R0 * 32;  // linear dest (shorts); hw adds lane*16B
    bG[p] = Bt + (size_t)(n0 + R0 + (lane >> 2)) * KK + kd * 8;
  }

  f32x4 acc[2][4];
#pragma unroll
  for (int m = 0; m < 2; ++m)
#pragma unroll
    for (int n = 0; n < 4; ++n) acc[m][n] = (f32x4)0.0f;

  // ---- prologue: stage tile 0, prefetch A regs for tile 1 ----
#pragma unroll
  for (int p = 0; p < 2; ++p) gl_lds16(bG[p], &Bs[0][bOff[p]]);
  f32x4 a0 = *(const f32x4*)aG;
  f32x4 a1 = *(const f32x4*)(aG + 4);
  *(bf16x8*)&As[0][aoff] = cvt8(a0, a1);
  a0 = *(const f32x4*)(aG + BK);
  a1 = *(const f32x4*)(aG + BK + 4);
  __syncthreads();

  int cur = 0;
  for (int t = 0; t < NT; ++t) {
    if (t + 1 < NT) {
      // issue next-tile staging BEFORE compute (hidden under MFMA; drained at barrier)
#pragma unroll
      for (int p = 0; p < 2; ++p) gl_lds16(bG[p] + (size_t)(t + 1) * BK, &Bs[cur ^ 1][bOff[p]]);
      *(bf16x8*)&As[cur ^ 1][aoff] = cvt8(a0, a1);
      int t2 = (t + 2 < NT) ? t + 2 : t;
      a0 = *(const f32x4*)(aG + (size_t)t2 * BK);
      a1 = *(const f32x4*)(aG + (size_t)t2 * BK + 4);
    }
    // ---- fragments + MFMA from buf[cur] ----
    const int sw = ((lrow >> 1) & 3);
    bf16x8 af[2], bfr[4];
#pragma unroll
    for (int m = 0; m < 2; ++m) {
      int r = wr * 32 + m * 16 + lrow;
      af[m] = *(const bf16x8*)&As[cur][r * 32 + ((kh ^ sw) << 3)];
    }
#pragma unroll
    for (int n = 0; n < 4; ++n) {
      int r = wc * 64 + n * 16 + lrow;
      bfr[n] = *(const bf16x8*)&Bs[cur][r * 32 + ((kh ^ sw) << 3)];
    }
#pragma unroll
    for (int m = 0; m < 2; ++m)
#pragma unroll
      for (int n = 0; n < 4; ++n)
        acc[m][n] = __builtin_amdgcn_mfma_f32_16x16x32_bf16(af[m], bfr[n], acc[m][n], 0, 0, 0);
    __syncthreads();
    cur ^= 1;
  }

  // ---- write Xp into p1 (C/D layout: col = lane&15, row = (lane>>4)*4 + reg) ----
#pragma unroll
  for (int m = 0; m < 2; ++m)
#pragma unroll
    for (int n = 0; n < 4; ++n)
#pragma unroll
      for (int r = 0; r < 4; ++r) {
        int row = m0 + wr * 32 + m * 16 + kh * 4 + r;
        int col = n0 + wc * 64 + n * 16 + lrow;
        out[(size_t)row * OUTW + 1 + col] = acc[m][n][r];
      }
}

// ---------------- epilogue: expand features from p1 ----------------
__global__ __launch_bounds__(512) void epi_k(float* __restrict__ out) {
  const int r = blockIdx.x;
  const int c = threadIdx.x;  // 0..511
  float* row = out + (size_t)r * OUTW;
  __shared__ float s[NN];
  float xp = row[1 + c];
  s[c] = xp;
  __syncthreads();
  float p2 = xp * xp;
  float p3 = p2 * xp;
  float sq = sqrtf(fabsf(xp) + 1e-8f);
  float pr = (c < 511) ? s[0] * s[c + 1] : s[1] * s[2];
  if (c == 0) row[0] = 1.0f;
  row[513 + c] = p2;
  row[1025 + c] = p3;
  row[1537 + c] = pr;
  row[2049 + c] = sq;
}

// ---------------- fallback (no workspace): round-1 path ----------------
#define FBM 128
#define FBN 128
#define FPAD 40

__global__ __launch_bounds__(256) void gemm_k(const float* __restrict__ A,
                                              const float* __restrict__ B,
                                              float* __restrict__ out) {
  __shared__ __align__(16) short Asf[FBM][FPAD];
  __shared__ __align__(16) short Bsf[FBN][FPAD];
  const int tid = threadIdx.x;
  const int bx = blockIdx.x;
  const int m0 = (bx >> 2) * FBM;
  const int n0 = (bx & 3) * FBN;
  const int wid = tid >> 6, lane = tid & 63;
  const int wr = wid >> 1, wc = wid & 1;
  const int lrow = lane & 15, kh = lane >> 4;
  f32x4 acc[4][4];
#pragma unroll
  for (int i = 0; i < 4; i++)
#pragma unroll
    for (int j = 0; j < 4; j++) acc[i][j] = (f32x4)0.0f;
  for (int k0 = 0; k0 < KK; k0 += BK) {
#pragma unroll
    for (int i = 0; i < 4; i++) {
      int fid = i * 256 + tid;
      int ar = fid >> 3, ac = (fid & 7) << 2;
      f32x4 v = *(const f32x4*)(A + (size_t)(m0 + ar) * KK + (k0 + ac));
      short h0 = f2bf(v[0]), h1 = f2bf(v[1]), h2 = f2bf(v[2]), h3 = f2bf(v[3]);
      Asf[ar][ac] = h0; Asf[ar][ac + 1] = h1; Asf[ar][ac + 2] = h2; Asf[ar][ac + 3] = h3;
    }
#pragma unroll
    for (int i = 0; i < 4; i++) {
      int fid = i * 256 + tid;
      int br = fid >> 5, bc = (fid & 31) << 2;
      f32x4 v = *(const f32x4*)(B + (size_t)(k0 + br) * NN + (n0 + bc));
#pragma unroll
      for (int j = 0; j < 4; j++) Bsf[bc + j][br] = f2bf(v[j]);
    }
    __syncthreads();
    bf16x8 af[4], bf[4];
#pragma unroll
    for (int m = 0; m < 4; m++) af[m] = *(const bf16x8*)&Asf[wr * 64 + m * 16 + lrow][kh * 8];
#pragma unroll
    for (int n = 0; n < 4; n++) bf[n] = *(const bf16x8*)&Bsf[wc * 64 + n * 16 + lrow][kh * 8];
#pragma unroll
    for (int m = 0; m < 4; m++)
#pragma unroll
      for (int n = 0; n < 4; n++)
        acc[m][n] = __builtin_amdgcn_mfma_f32_16x16x32_bf16(af[m], bf[n], acc[m][n], 0, 0, 0);
    __syncthreads();
  }
#pragma unroll
  for (int m = 0; m < 4; m++)
#pragma unroll
    for (int n = 0; n < 4; n++)
#pragma unroll
      for (int r = 0; r < 4; r++) {
        int row = m0 + wr * 64 + m * 16 + kh * 4 + r;
        int col = n0 + wc * 64 + n * 16 + lrow;
        out[(size_t)row * OUTW + 1 + col] = acc[m][n][r];
      }
}

extern "C" void kernel_launch(void* const* d_in, const int* in_sizes, int n_in,
                              void* d_out, int out_size, void* d_ws, size_t ws_size,
                              hipStream_t stream) {
  const float* X = (const float*)d_in[0];
  const float* P = (const float*)d_in[1];
  float* out = (float*)d_out;
  (void)in_sizes; (void)n_in; (void)out_size;

  if (ws_size >= (size_t)NN * KK * sizeof(short)) {
    short* Bt = (short*)d_ws;
    prep_b<<<dim3(256), dim3(256), 0, stream>>>(P, Bt);
    gemm3<<<dim3((MM / BM) * (NN / BN)), dim3(256), 0, stream>>>(X, Bt, out);
  } else {
    gemm_k<<<dim3(512), dim3(256), 0, stream>>>(X, P, out);
  }
  epi_k<<<dim3(MM), dim3(512), 0, stream>>>(out);
}

// Round 4
// 127.554 us; speedup vs baseline: 1.0859x; 1.0859x over previous
//
#include <hip/hip_runtime.h>
#include <hip/hip_bf16.h>
#include <math.h>

// Polynomial feature map: Xp = X @ P; out = [bias | Xp | Xp^2 | Xp^3 | pairs | sqrt(|Xp|+eps)]
// X: [16384, 2048] f32, P: [2048, 512] f32, out: [16384, 2561] f32.
// pairs (triu k=1, first 512): c<511 -> Xp[:,0]*Xp[:,c+1]; c==511 -> Xp[:,1]*Xp[:,2]
//
// Path: prep_b (P -> Bt bf16 [512][2048] in ws) ; gemm4 (m97 geometry: 128x128 tile,
// 4 waves at 64x64, 16 MFMA + 8 ds_read per K-step, dbuf, grid 512) writes p1 ;
// epi_k expands remaining regions reading p1 back (L2/L3-hot).

typedef __attribute__((ext_vector_type(4))) float f32x4;
typedef __attribute__((ext_vector_type(8))) short bf16x8;

#define MM 16384
#define NN 512
#define KK 2048
#define OUTW 2561

#define BM 128
#define BN 128
#define BK 32
#define NT (KK / BK)  // 64

__device__ __forceinline__ short f2bf(float x) {
  union { __hip_bfloat16 b; short s; } u;
  u.b = __float2bfloat16(x);  // hw RNE; compiler pairs into v_cvt_pk_bf16_f32
  return u.s;
}

__device__ __forceinline__ bf16x8 cvt8(f32x4 a, f32x4 b) {
  bf16x8 r;
  r[0] = f2bf(a[0]); r[1] = f2bf(a[1]); r[2] = f2bf(a[2]); r[3] = f2bf(a[3]);
  r[4] = f2bf(b[0]); r[5] = f2bf(b[1]); r[6] = f2bf(b[2]); r[7] = f2bf(b[3]);
  return r;
}

__device__ __forceinline__ void gl_lds16(const void* g, void* l) {
  __builtin_amdgcn_global_load_lds((const __attribute__((address_space(1))) unsigned int*)g,
                                   (__attribute__((address_space(3))) unsigned int*)l, 16, 0, 0);
}

// ---------------- prep: P [K][N] f32 -> Bt [N][K] bf16 ----------------
__global__ __launch_bounds__(256) void prep_b(const float* __restrict__ P, short* __restrict__ Bt) {
  __shared__ float ts[64][65];
  const int tid = threadIdx.x;
  const int k0 = (blockIdx.x >> 3) * 64;  // 32 k-blocks
  const int n0 = (blockIdx.x & 7) * 64;   // 8 n-blocks
#pragma unroll
  for (int j = 0; j < 16; ++j) {
    int idx = j * 256 + tid;
    int kr = idx >> 6, nc = idx & 63;
    ts[kr][nc] = P[(size_t)(k0 + kr) * NN + n0 + nc];
  }
  __syncthreads();
#pragma unroll
  for (int j = 0; j < 16; ++j) {
    int idx = j * 256 + tid;
    int nr = idx >> 6, kc = idx & 63;
    Bt[(size_t)(n0 + nr) * KK + k0 + kc] = f2bf(ts[kc][nr]);
  }
}

// ---------------- GEMM (m97 geometry): Xp -> out p1 region ----------------
// LDS tiles [rows][32 bf16] (64B rows, 4x 16B slots). Swizzle: slot' = slot ^ ((row>>1)&3)
// (verified 0 bank conflicts in round 3). B staged by global_load_lds (linear dest);
// swizzle realized by permuting the per-lane GLOBAL source k-slot (rule #21).
__global__ __launch_bounds__(256) void gemm4(const float* __restrict__ X,
                                             const short* __restrict__ Bt,
                                             float* __restrict__ out) {
  __shared__ short As[2][BM * BK];   // 8 KB each
  __shared__ short Bs[2][BN * BK];   // 8 KB each

  const int tid = threadIdx.x;
  const int wid = tid >> 6, lane = tid & 63;
  const int lrow = lane & 15, kh = lane >> 4;
  const int wr = wid >> 1, wc = wid & 1;  // 2x2 wave grid; wave tile 64 x 64

  // XCD-bijective swizzle (512 blocks, 512%8==0): each XCD gets 64 consecutive tiles;
  // 4 consecutive tiles share the same A-row panel (n-tile fastest).
  const int bid = blockIdx.x;
  const int tile = (bid & 7) * 64 + (bid >> 3);
  const int m0 = (tile >> 2) * BM;   // 128 row-blocks
  const int n0 = (tile & 3) * BN;    // 4 col-blocks

  // A staging: sub-iter j in {0,1}: row = j*64 + (tid>>2), 8 floats at k = (tid&3)*8
  const int ar0 = tid >> 2, akq = tid & 3;
  const float* aG = X + (size_t)(m0 + ar0) * KK + akq * 8;
  int aoff[2];
#pragma unroll
  for (int j = 0; j < 2; ++j) {
    int row = j * 64 + ar0;
    aoff[j] = row * 32 + ((akq ^ ((row >> 1) & 3)) << 3);  // shorts (16B slot)
  }

  // B staging: 2 wave-loads/wave; load p covers B-rows (p*4+wid)*16 .. +15
  const int kd = (lane & 3) ^ ((lane >> 3) & 3);  // pre-swizzled source k-slot
  const short* bG[2];
  int bOff[2];
#pragma unroll
  for (int p = 0; p < 2; ++p) {
    int R0 = (p * 4 + wid) * 16;
    bOff[p] = R0 * 32;  // linear dest (shorts); hw adds lane*16B
    bG[p] = Bt + (size_t)(n0 + R0 + (lane >> 2)) * KK + kd * 8;
  }

  f32x4 acc[4][4];
#pragma unroll
  for (int m = 0; m < 4; ++m)
#pragma unroll
    for (int n = 0; n < 4; ++n) acc[m][n] = (f32x4)0.0f;

  // ---- prologue: stage tile 0, prefetch A regs for tile 1 ----
#pragma unroll
  for (int p = 0; p < 2; ++p) gl_lds16(bG[p], &Bs[0][bOff[p]]);
  f32x4 a0 = *(const f32x4*)aG;
  f32x4 a1 = *(const f32x4*)(aG + 4);
  f32x4 a2 = *(const f32x4*)(aG + (size_t)64 * KK);
  f32x4 a3 = *(const f32x4*)(aG + (size_t)64 * KK + 4);
  *(bf16x8*)&As[0][aoff[0]] = cvt8(a0, a1);
  *(bf16x8*)&As[0][aoff[1]] = cvt8(a2, a3);
  a0 = *(const f32x4*)(aG + BK);
  a1 = *(const f32x4*)(aG + BK + 4);
  a2 = *(const f32x4*)(aG + (size_t)64 * KK + BK);
  a3 = *(const f32x4*)(aG + (size_t)64 * KK + BK + 4);
  __syncthreads();

  int cur = 0;
  for (int t = 0; t < NT; ++t) {
    if (t + 1 < NT) {
      // issue next-tile staging BEFORE compute (hidden under MFMA; drained at barrier)
#pragma unroll
      for (int p = 0; p < 2; ++p) gl_lds16(bG[p] + (size_t)(t + 1) * BK, &Bs[cur ^ 1][bOff[p]]);
      *(bf16x8*)&As[cur ^ 1][aoff[0]] = cvt8(a0, a1);
      *(bf16x8*)&As[cur ^ 1][aoff[1]] = cvt8(a2, a3);
      int t2 = (t + 2 < NT) ? t + 2 : t;  // clamp; redundant but in-bounds at tail
      const float* ap = aG + (size_t)t2 * BK;
      a0 = *(const f32x4*)ap;
      a1 = *(const f32x4*)(ap + 4);
      a2 = *(const f32x4*)(ap + (size_t)64 * KK);
      a3 = *(const f32x4*)(ap + (size_t)64 * KK + 4);
    }
    // ---- fragments + MFMA from buf[cur]: 8 ds_read_b128, 16 MFMA ----
    const int sw = (lrow >> 1) & 3;
    bf16x8 af[4], bfr[4];
#pragma unroll
    for (int m = 0; m < 4; ++m) {
      int r = wr * 64 + m * 16 + lrow;
      af[m] = *(const bf16x8*)&As[cur][r * 32 + ((kh ^ sw) << 3)];
    }
#pragma unroll
    for (int n = 0; n < 4; ++n) {
      int r = wc * 64 + n * 16 + lrow;
      bfr[n] = *(const bf16x8*)&Bs[cur][r * 32 + ((kh ^ sw) << 3)];
    }
#pragma unroll
    for (int m = 0; m < 4; ++m)
#pragma unroll
      for (int n = 0; n < 4; ++n)
        acc[m][n] = __builtin_amdgcn_mfma_f32_16x16x32_bf16(af[m], bfr[n], acc[m][n], 0, 0, 0);
    __syncthreads();
    cur ^= 1;
  }

  // ---- write Xp into p1 (C/D layout: col = lane&15, row = (lane>>4)*4 + reg) ----
#pragma unroll
  for (int m = 0; m < 4; ++m)
#pragma unroll
    for (int n = 0; n < 4; ++n)
#pragma unroll
      for (int r = 0; r < 4; ++r) {
        int row = m0 + wr * 64 + m * 16 + kh * 4 + r;
        int col = n0 + wc * 64 + n * 16 + lrow;
        out[(size_t)row * OUTW + 1 + col] = acc[m][n][r];
      }
}

// ---------------- epilogue: expand features from p1 ----------------
__global__ __launch_bounds__(512) void epi_k(float* __restrict__ out) {
  const int r = blockIdx.x;
  const int c = threadIdx.x;  // 0..511
  float* row = out + (size_t)r * OUTW;
  __shared__ float s[NN];
  float xp = row[1 + c];
  s[c] = xp;
  __syncthreads();
  float p2 = xp * xp;
  float p3 = p2 * xp;
  float sq = sqrtf(fabsf(xp) + 1e-8f);
  float pr = (c < 511) ? s[0] * s[c + 1] : s[1] * s[2];
  if (c == 0) row[0] = 1.0f;
  row[513 + c] = p2;
  row[1025 + c] = p3;
  row[1537 + c] = pr;
  row[2049 + c] = sq;
}

// ---------------- fallback (no workspace): round-1 path ----------------
#define FBM 128
#define FBN 128
#define FPAD 40

__global__ __launch_bounds__(256) void gemm_k(const float* __restrict__ A,
                                              const float* __restrict__ B,
                                              float* __restrict__ out) {
  __shared__ __align__(16) short Asf[FBM][FPAD];
  __shared__ __align__(16) short Bsf[FBN][FPAD];
  const int tid = threadIdx.x;
  const int bx = blockIdx.x;
  const int m0 = (bx >> 2) * FBM;
  const int n0 = (bx & 3) * FBN;
  const int wid = tid >> 6, lane = tid & 63;
  const int wr = wid >> 1, wc = wid & 1;
  const int lrow = lane & 15, kh = lane >> 4;
  f32x4 acc[4][4];
#pragma unroll
  for (int i = 0; i < 4; i++)
#pragma unroll
    for (int j = 0; j < 4; j++) acc[i][j] = (f32x4)0.0f;
  for (int k0 = 0; k0 < KK; k0 += BK) {
#pragma unroll
    for (int i = 0; i < 4; i++) {
      int fid = i * 256 + tid;
      int ar = fid >> 3, ac = (fid & 7) << 2;
      f32x4 v = *(const f32x4*)(A + (size_t)(m0 + ar) * KK + (k0 + ac));
      short h0 = f2bf(v[0]), h1 = f2bf(v[1]), h2 = f2bf(v[2]), h3 = f2bf(v[3]);
      Asf[ar][ac] = h0; Asf[ar][ac + 1] = h1; Asf[ar][ac + 2] = h2; Asf[ar][ac + 3] = h3;
    }
#pragma unroll
    for (int i = 0; i < 4; i++) {
      int fid = i * 256 + tid;
      int br = fid >> 5, bc = (fid & 31) << 2;
      f32x4 v = *(const f32x4*)(B + (size_t)(k0 + br) * NN + (n0 + bc));
#pragma unroll
      for (int j = 0; j < 4; j++) Bsf[bc + j][br] = f2bf(v[j]);
    }
    __syncthreads();
    bf16x8 af[4], bf[4];
#pragma unroll
    for (int m = 0; m < 4; m++) af[m] = *(const bf16x8*)&Asf[wr * 64 + m * 16 + lrow][kh * 8];
#pragma unroll
    for (int n = 0; n < 4; n++) bf[n] = *(const bf16x8*)&Bsf[wc * 64 + n * 16 + lrow][kh * 8];
#pragma unroll
    for (int m = 0; m < 4; m++)
#pragma unroll
      for (int n = 0; n < 4; n++)
        acc[m][n] = __builtin_amdgcn_mfma_f32_16x16x32_bf16(af[m], bf[n], acc[m][n], 0, 0, 0);
    __syncthreads();
  }
#pragma unroll
  for (int m = 0; m < 4; m++)
#pragma unroll
    for (int n = 0; n < 4; n++)
#pragma unroll
      for (int r = 0; r < 4; r++) {
        int row = m0 + wr * 64 + m * 16 + kh * 4 + r;
        int col = n0 + wc * 64 + n * 16 + lrow;
        out[(size_t)row * OUTW + 1 + col] = acc[m][n][r];
      }
}

extern "C" void kernel_launch(void* const* d_in, const int* in_sizes, int n_in,
                              void* d_out, int out_size, void* d_ws, size_t ws_size,
                              hipStream_t stream) {
  const float* X = (const float*)d_in[0];
  const float* P = (const float*)d_in[1];
  float* out = (float*)d_out;
  (void)in_sizes; (void)n_in; (void)out_size;

  if (ws_size >= (size_t)NN * KK * sizeof(short)) {
    short* Bt = (short*)d_ws;
    prep_b<<<dim3(256), dim3(256), 0, stream>>>(P, Bt);
    gemm4<<<dim3((MM / BM) * (NN / BN)), dim3(256), 0, stream>>>(X, Bt, out);
  } else {
    gemm_k<<<dim3(512), dim3(256), 0, stream>>>(X, P, out);
  }
  epi_k<<<dim3(MM), dim3(512), 0, stream>>>(out);
}